// Round 1
// baseline (506.721 us; speedup 1.0000x reference)
//
#include <hip/hip_runtime.h>

typedef unsigned short u16;
typedef short s16x8 __attribute__((ext_vector_type(8)));
typedef float f32x4 __attribute__((ext_vector_type(4)));

// ---------------- bf16 helpers (RNE) ----------------
static __device__ __forceinline__ u16 f2b(float f) {
  union { float f; unsigned u; } v; v.f = f;
  unsigned r = v.u + 0x7fffu + ((v.u >> 16) & 1u);
  return (u16)(r >> 16);
}
static __device__ __forceinline__ float b2f(u16 u) {
  union { unsigned u; float f; } v; v.u = ((unsigned)u) << 16;
  return v.f;
}

#define MFMA16(a, b, c) __builtin_amdgcn_mfma_f32_16x16x32_bf16((a), (b), (c), 0, 0, 0)

// ---------------- prep kernels ----------------
__global__ void k_cast_x(const float* __restrict__ src, u16* __restrict__ dst, int n4) {
  int i = blockIdx.x * blockDim.x + threadIdx.x;
  if (i >= n4) return;
  float4 v = ((const float4*)src)[i];
  ushort4 o;
  o.x = f2b(v.x); o.y = f2b(v.y); o.z = f2b(v.z); o.w = f2b(v.w);
  ((ushort4*)dst)[i] = o;
}

// W [1024 u][1024 n] f32 -> Wt [1024 n][1024 u] bf16
__global__ void k_transpose_w(const float* wq, const float* wk, const float* wv, const float* wo,
                              u16* dq, u16* dk, u16* dv, u16* dwo) {
  const float* src; u16* dst;
  int z = blockIdx.z;
  if (z == 0)      { src = wq; dst = dq; }
  else if (z == 1) { src = wk; dst = dk; }
  else if (z == 2) { src = wv; dst = dv; }
  else             { src = wo; dst = dwo; }
  __shared__ float t[32][33];
  int x0 = blockIdx.x * 32, y0 = blockIdx.y * 32;
  int tx = threadIdx.x, ty = threadIdx.y;
#pragma unroll
  for (int k = 0; k < 4; k++) t[ty + 8 * k][tx] = src[(size_t)(y0 + ty + 8 * k) * 1024 + x0 + tx];
  __syncthreads();
#pragma unroll
  for (int k = 0; k < 4; k++) dst[(size_t)(x0 + ty + 8 * k) * 1024 + y0 + tx] = f2b(t[tx][ty + 8 * k]);
}

// ekb: [16][144][64] bf16 (m>=129 zero) ; evt: [16][64][160] bf16 (ev^T per head, m>=129 zero)
__global__ void k_prep_rel(const float* __restrict__ ek, const float* __restrict__ ev,
                           u16* __restrict__ ekb, u16* __restrict__ evt) {
  int i = blockIdx.x * blockDim.x + threadIdx.x;
  if (i < 16 * 144 * 64) {
    int h = i / (144 * 64); int rem = i % (144 * 64); int m = rem / 64; int d = rem % 64;
    ekb[i] = (m < 129) ? f2b(ek[((size_t)h * 129 + m) * 64 + d]) : (u16)0;
  }
  if (i < 16 * 64 * 160) {
    int h = i / (64 * 160); int rem = i % (64 * 160); int d = rem / 160; int mm = rem % 160;
    evt[i] = (mm < 129) ? f2b(ev[((size_t)h * 129 + mm) * 64 + d]) : (u16)0;
  }
}

// ---------------- bf16 MFMA GEMM: C[4096][1024] = A[4096][1024] * Bt[1024][1024]^T ----------------
// mode 0: write bf16 to [B][H][L][D]      (Q / K)
// mode 1: write bf16 to [B][H][D][L]      (V transposed)
// mode 2: write f32  row-major + bias     (final output)
__global__ __launch_bounds__(256) void k_gemm_bt(const u16* __restrict__ A, const u16* __restrict__ Bt,
                                                 void* __restrict__ Cout, const float* __restrict__ bias,
                                                 int mode) {
  __shared__ u16 As[128 * 32];
  __shared__ u16 Bs[128 * 32];
  int tid = threadIdx.x;
  int w = tid >> 6, lane = tid & 63;
  int wrw = w >> 1, wcw = w & 1, lr = lane & 15, lk = lane >> 4;
  int m0 = blockIdx.y * 128, n0 = blockIdx.x * 128;
  f32x4 acc[4][4] = {};
  int soff = tid * 8;
  int sr = soff >> 5, sc = soff & 31;
  for (int k0 = 0; k0 < 1024; k0 += 32) {
    __syncthreads();
    *(uint4*)&As[soff]        = *(const uint4*)&A [(size_t)(m0 + sr) * 1024      + k0 + sc];
    *(uint4*)&As[soff + 2048] = *(const uint4*)&A [(size_t)(m0 + 64 + sr) * 1024 + k0 + sc];
    *(uint4*)&Bs[soff]        = *(const uint4*)&Bt[(size_t)(n0 + sr) * 1024      + k0 + sc];
    *(uint4*)&Bs[soff + 2048] = *(const uint4*)&Bt[(size_t)(n0 + 64 + sr) * 1024 + k0 + sc];
    __syncthreads();
    s16x8 af[4], bfr[4];
#pragma unroll
    for (int mt = 0; mt < 4; mt++) af[mt]  = *(const s16x8*)&As[(wrw * 64 + mt * 16 + lr) * 32 + lk * 8];
#pragma unroll
    for (int nt = 0; nt < 4; nt++) bfr[nt] = *(const s16x8*)&Bs[(wcw * 64 + nt * 16 + lr) * 32 + lk * 8];
#pragma unroll
    for (int mt = 0; mt < 4; mt++)
#pragma unroll
      for (int nt = 0; nt < 4; nt++)
        acc[mt][nt] = MFMA16(af[mt], bfr[nt], acc[mt][nt]);
  }
#pragma unroll
  for (int mt = 0; mt < 4; mt++)
#pragma unroll
    for (int nt = 0; nt < 4; nt++)
#pragma unroll
      for (int r = 0; r < 4; r++) {
        int row = m0 + wrw * 64 + mt * 16 + lk * 4 + r;
        int col = n0 + wcw * 64 + nt * 16 + lr;
        float v = acc[mt][nt][r];
        if (mode == 2) {
          ((float*)Cout)[(size_t)row * 1024 + col] = v + bias[col];
        } else {
          int bb = row >> 10, l = row & 1023;
          int hh = col >> 6, dd = col & 63;
          if (mode == 0)
            ((u16*)Cout)[((size_t)(bb * 16 + hh)) * 65536 + (size_t)l * 64 + dd] = f2b(v);
          else
            ((u16*)Cout)[((size_t)(bb * 16 + hh)) * 65536 + (size_t)dd * 1024 + l] = f2b(v);
        }
      }
}

// ---------------- fused relative-position attention ----------------
// Grid: B*H*16 blocks (one per (b,h, 64-row q tile)), 256 threads.
// LDS carve (bytes):
//   q_s   @ 0      : 64*64  bf16 = 8192
//   qm_s  @ 8192   : 64*133 f32  = 34048   (overlaid by wrb_s after pass B)
//   P_s   @ 42240  : 64*136 bf16 = 17408
//   wr_s  @ 59648  : 64*132 f32  = 33792   -> total 93440
#define SM_BYTES 93440
__global__ __launch_bounds__(256) void k_attn(const u16* __restrict__ Qg, const u16* __restrict__ Kg,
                                              const u16* __restrict__ Vt, const u16* __restrict__ ekb,
                                              const u16* __restrict__ evt, const float* __restrict__ pmask,
                                              u16* __restrict__ Og) {
  __shared__ alignas(16) char smem[SM_BYTES];
  u16*   q_s   = (u16*)(smem);
  float* qm_s  = (float*)(smem + 8192);
  u16*   wrb_s = (u16*)(smem + 8192);     // overlay: valid only after qm_s is dead
  u16*   P_s   = (u16*)(smem + 42240);
  float* wr_s  = (float*)(smem + 59648);

  int tid = threadIdx.x;
  int w = tid >> 6, lane = tid & 63;
  int lr = lane & 15, lk = lane >> 4;
  int bh = blockIdx.x >> 4, it = blockIdx.x & 15;
  int b = bh >> 4, h = bh & 15;
  int i0 = it * 64;

  {
    const uint4* src = (const uint4*)(Qg + (size_t)bh * 65536 + (size_t)i0 * 64);
    uint4* dst = (uint4*)q_s;
    for (int t = tid; t < 512; t += 256) dst[t] = src[t];
  }
  for (int t = tid; t < 64 * 132; t += 256) wr_s[t] = 0.f;
  __syncthreads();

  // qm[i][m] = q_i . ek[h][m]  (M padded to 144; keep m<133)
  {
    s16x8 aq0 = *(const s16x8*)&q_s[(w * 16 + lr) * 64 + lk * 8];
    s16x8 aq1 = *(const s16x8*)&q_s[(w * 16 + lr) * 64 + 32 + lk * 8];
#pragma unroll
    for (int nt = 0; nt < 9; nt++) {
      f32x4 c = {};
      const u16* ekp = &ekb[((size_t)h * 144 + nt * 16 + lr) * 64 + lk * 8];
      s16x8 b0 = *(const s16x8*)ekp;
      s16x8 b1 = *(const s16x8*)(ekp + 32);
      c = MFMA16(aq0, b0, c);
      c = MFMA16(aq1, b1, c);
      int mcol = nt * 16 + lr;
      if (mcol < 133) {
#pragma unroll
        for (int r = 0; r < 4; r++) qm_s[(w * 16 + lk * 4 + r) * 133 + mcol] = c[r];
      }
    }
  }
  __syncthreads();

  s16x8 aq[2];
  aq[0] = *(const s16x8*)&q_s[(w * 16 + lr) * 64 + lk * 8];
  aq[1] = *(const s16x8*)&q_s[(w * 16 + lr) * 64 + 32 + lk * 8];

  float mrow[4] = {-3e38f, -3e38f, -3e38f, -3e38f};
  float srow[4] = {0.f, 0.f, 0.f, 0.f};

  // ---- pass A: exact row max + sum ----
  for (int jt = 0; jt < 8; jt++) {
    int j0 = jt * 128;
    float sv[8][4];
#pragma unroll
    for (int nt = 0; nt < 8; nt++) {
      f32x4 c = {};
      const u16* kp = &Kg[((size_t)bh * 1024 + j0 + nt * 16 + lr) * 64 + lk * 8];
      s16x8 b0 = *(const s16x8*)kp;
      s16x8 b1 = *(const s16x8*)(kp + 32);
      c = MFMA16(aq[0], b0, c);
      c = MFMA16(aq[1], b1, c);
      int j = j0 + nt * 16 + lr;
      float mk = pmask[b * 1024 + j] * -1e9f;
#pragma unroll
      for (int r = 0; r < 4; r++) {
        int i_loc = w * 16 + lk * 4 + r;
        int dl = j - (i0 + i_loc);
        dl = dl < -64 ? -64 : (dl > 64 ? 64 : dl);
        sv[nt][r] = (c[r] + qm_s[i_loc * 133 + dl + 64]) * 0.125f + mk;
      }
    }
#pragma unroll
    for (int r = 0; r < 4; r++) {
      float mx = sv[0][r];
#pragma unroll
      for (int nt = 1; nt < 8; nt++) mx = fmaxf(mx, sv[nt][r]);
#pragma unroll
      for (int o = 1; o < 16; o <<= 1) mx = fmaxf(mx, __shfl_xor(mx, o));
      float nm = fmaxf(mrow[r], mx);
      float se = 0.f;
#pragma unroll
      for (int nt = 0; nt < 8; nt++) se += __expf(sv[nt][r] - nm);
#pragma unroll
      for (int o = 1; o < 16; o <<= 1) se += __shfl_xor(se, o);
      srow[r] = srow[r] * __expf(mrow[r] - nm) + se;
      mrow[r] = nm;
    }
  }

  // ---- pass B: P~ = exp(S - m); PV MFMA + banded wr accumulation ----
  f32x4 oacc[4] = {};
  for (int jt = 0; jt < 8; jt++) {
    int j0 = jt * 128;
#pragma unroll
    for (int nt = 0; nt < 8; nt++) {
      f32x4 c = {};
      const u16* kp = &Kg[((size_t)bh * 1024 + j0 + nt * 16 + lr) * 64 + lk * 8];
      s16x8 b0 = *(const s16x8*)kp;
      s16x8 b1 = *(const s16x8*)(kp + 32);
      c = MFMA16(aq[0], b0, c);
      c = MFMA16(aq[1], b1, c);
      int j = j0 + nt * 16 + lr;
      float mk = pmask[b * 1024 + j] * -1e9f;
#pragma unroll
      for (int r = 0; r < 4; r++) {
        int i_loc = w * 16 + lk * 4 + r;
        int dl = j - (i0 + i_loc);
        dl = dl < -64 ? -64 : (dl > 64 ? 64 : dl);
        float sval = (c[r] + qm_s[i_loc * 133 + dl + 64]) * 0.125f + mk;
        P_s[i_loc * 136 + nt * 16 + lr] = f2b(__expf(sval - mrow[r]));
      }
    }
    __syncthreads();
    // PV: oacc[i][d] += P~ . V  (B^T operand = Vt[d][j])
    {
      s16x8 ap[4];
#pragma unroll
      for (int kk = 0; kk < 4; kk++) ap[kk] = *(const s16x8*)&P_s[(w * 16 + lr) * 136 + kk * 32 + lk * 8];
#pragma unroll
      for (int nt = 0; nt < 4; nt++) {
        const u16* vp = &Vt[((size_t)bh * 64 + nt * 16 + lr) * 1024 + j0 + lk * 8];
#pragma unroll
        for (int kk = 0; kk < 4; kk++) {
          s16x8 bv = *(const s16x8*)(vp + kk * 32);
          oacc[nt] = MFMA16(ap[kk], bv, oacc[nt]);
        }
      }
    }
    // wr: interior buckets are 1:1 with j; edges are prefix/suffix sums
    {
      int iw = tid >> 2, sub = tid & 3;
      int ig = i0 + iw;
      float lsum = 0.f, rsum = 0.f;
#pragma unroll
      for (int kk = 0; kk < 32; kk++) {
        int jj = kk * 4 + sub;
        float p = b2f(P_s[iw * 136 + jj]);
        int dl = (j0 + jj) - ig;
        if (dl <= -64) lsum += p;
        else if (dl >= 64) rsum += p;
        else wr_s[iw * 132 + dl + 64] = p;
      }
      lsum += __shfl_xor(lsum, 1); lsum += __shfl_xor(lsum, 2);
      rsum += __shfl_xor(rsum, 1); rsum += __shfl_xor(rsum, 2);
      if (sub == 0) { wr_s[iw * 132] += lsum; wr_s[iw * 132 + 128] += rsum; }
    }
    __syncthreads();
  }

  // wr -> bf16 (overlay on dead qm_s region), K padded to 160
  for (int t = tid; t < 64 * 160; t += 256) {
    int i = t / 160, mm = t % 160;
    wrb_s[t] = (mm < 129) ? f2b(wr_s[i * 132 + mm]) : (u16)0;
  }
  __syncthreads();
  // oacc += wr . ev  (B^T operand = evt[d][m])
  {
    s16x8 aw[5];
#pragma unroll
    for (int kk = 0; kk < 5; kk++) aw[kk] = *(const s16x8*)&wrb_s[(w * 16 + lr) * 160 + kk * 32 + lk * 8];
#pragma unroll
    for (int nt = 0; nt < 4; nt++) {
      const u16* ep = &evt[((size_t)h * 64 + nt * 16 + lr) * 160 + lk * 8];
#pragma unroll
      for (int kk = 0; kk < 5; kk++) {
        s16x8 be = *(const s16x8*)(ep + kk * 32);
        oacc[nt] = MFMA16(aw[kk], be, oacc[nt]);
      }
    }
  }
  // write O[(b,l)][(h,d)] bf16, scaled by 1/s
#pragma unroll
  for (int nt = 0; nt < 4; nt++)
#pragma unroll
    for (int r = 0; r < 4; r++) {
      int i_loc = w * 16 + lk * 4 + r;
      float v = oacc[nt][r] / srow[r];
      Og[((size_t)(b * 1024 + i0 + i_loc)) * 1024 + h * 64 + nt * 16 + lr] = f2b(v);
    }
}

// ---------------- launch ----------------
// ws layout (bytes), total ~48.6 MB:
#define OFF_XB   0u
#define OFF_WQT  8388608u
#define OFF_WKT  10485760u
#define OFF_WVT  12582912u
#define OFF_WOT  14680064u
#define OFF_Q    16777216u
#define OFF_K    25165824u
#define OFF_VT   33554432u
#define OFF_O    41943040u
#define OFF_EKB  50331648u
#define OFF_EVT  50626560u

extern "C" void kernel_launch(void* const* d_in, const int* in_sizes, int n_in,
                              void* d_out, int out_size, void* d_ws, size_t ws_size,
                              hipStream_t stream) {
  const float* x  = (const float*)d_in[0];
  const float* pm = (const float*)d_in[1];
  const float* wq = (const float*)d_in[2];
  const float* wk = (const float*)d_in[3];
  const float* wv = (const float*)d_in[4];
  const float* wo = (const float*)d_in[5];
  const float* bo = (const float*)d_in[6];
  const float* ek = (const float*)d_in[7];
  const float* ev = (const float*)d_in[8];
  char* ws = (char*)d_ws;
  u16* Xb  = (u16*)(ws + OFF_XB);
  u16* Wqt = (u16*)(ws + OFF_WQT);
  u16* Wkt = (u16*)(ws + OFF_WKT);
  u16* Wvt = (u16*)(ws + OFF_WVT);
  u16* Wot = (u16*)(ws + OFF_WOT);
  u16* Qg  = (u16*)(ws + OFF_Q);
  u16* Kg  = (u16*)(ws + OFF_K);
  u16* Vtg = (u16*)(ws + OFF_VT);
  u16* Og  = (u16*)(ws + OFF_O);
  u16* EKB = (u16*)(ws + OFF_EKB);
  u16* EVT = (u16*)(ws + OFF_EVT);

  k_cast_x<<<4096, 256, 0, stream>>>(x, Xb, 1048576);
  {
    dim3 tb(32, 8), tg(32, 32, 4);
    k_transpose_w<<<tg, tb, 0, stream>>>(wq, wk, wv, wo, Wqt, Wkt, Wvt, Wot);
  }
  k_prep_rel<<<640, 256, 0, stream>>>(ek, ev, EKB, EVT);
  {
    dim3 gg(8, 32);
    k_gemm_bt<<<gg, 256, 0, stream>>>(Xb, Wqt, Qg,  nullptr, 0);
    k_gemm_bt<<<gg, 256, 0, stream>>>(Xb, Wkt, Kg,  nullptr, 0);
    k_gemm_bt<<<gg, 256, 0, stream>>>(Xb, Wvt, Vtg, nullptr, 1);
    k_attn<<<1024, 256, 0, stream>>>(Qg, Kg, Vtg, EKB, EVT, pm, Og);
    k_gemm_bt<<<gg, 256, 0, stream>>>(Og, Wot, d_out, bo, 2);
  }
}

// Round 2
// 314.916 us; speedup vs baseline: 1.6091x; 1.6091x over previous
//
#include <hip/hip_runtime.h>

typedef unsigned short u16;
typedef short s16x8 __attribute__((ext_vector_type(8)));
typedef float f32x4 __attribute__((ext_vector_type(4)));

// ---------------- bf16 helpers (RNE) ----------------
static __device__ __forceinline__ u16 f2b(float f) {
  union { float f; unsigned u; } v; v.f = f;
  unsigned r = v.u + 0x7fffu + ((v.u >> 16) & 1u);
  return (u16)(r >> 16);
}
static __device__ __forceinline__ float b2f(u16 u) {
  union { unsigned u; float f; } v; v.u = ((unsigned)u) << 16;
  return v.f;
}

#define MFMA16(a, b, c) __builtin_amdgcn_mfma_f32_16x16x32_bf16((a), (b), (c), 0, 0, 0)

// async global -> LDS, 16B per lane (dest = uniform base + lane*16)
static __device__ __forceinline__ void gload_lds16(const u16* g, u16* l) {
  __builtin_amdgcn_global_load_lds((const __attribute__((address_space(1))) void*)g,
                                   (__attribute__((address_space(3))) void*)l, 16, 0, 0);
}

// ---------------- prep kernels ----------------
__global__ void k_cast_x(const float* __restrict__ src, u16* __restrict__ dst, int n4) {
  int i = blockIdx.x * blockDim.x + threadIdx.x;
  if (i >= n4) return;
  float4 v = ((const float4*)src)[i];
  ushort4 o;
  o.x = f2b(v.x); o.y = f2b(v.y); o.z = f2b(v.z); o.w = f2b(v.w);
  ((ushort4*)dst)[i] = o;
}

// W [1024 u][1024 n] f32 -> Wt [1024 n][1024 u] bf16
__global__ void k_transpose_w(const float* wq, const float* wk, const float* wv, const float* wo,
                              u16* dq, u16* dk, u16* dv, u16* dwo) {
  const float* src; u16* dst;
  int z = blockIdx.z;
  if (z == 0)      { src = wq; dst = dq; }
  else if (z == 1) { src = wk; dst = dk; }
  else if (z == 2) { src = wv; dst = dv; }
  else             { src = wo; dst = dwo; }
  __shared__ float t[32][33];
  int x0 = blockIdx.x * 32, y0 = blockIdx.y * 32;
  int tx = threadIdx.x, ty = threadIdx.y;
#pragma unroll
  for (int k = 0; k < 4; k++) t[ty + 8 * k][tx] = src[(size_t)(y0 + ty + 8 * k) * 1024 + x0 + tx];
  __syncthreads();
#pragma unroll
  for (int k = 0; k < 4; k++) dst[(size_t)(x0 + ty + 8 * k) * 1024 + y0 + tx] = f2b(t[tx][ty + 8 * k]);
}

// ekb: [16][144][64] bf16 (m>=129 zero) ; evt: [16][64][160] bf16 (ev^T per head, m>=129 zero)
__global__ void k_prep_rel(const float* __restrict__ ek, const float* __restrict__ ev,
                           u16* __restrict__ ekb, u16* __restrict__ evt) {
  int i = blockIdx.x * blockDim.x + threadIdx.x;
  if (i < 16 * 144 * 64) {
    int h = i / (144 * 64); int rem = i % (144 * 64); int m = rem / 64; int d = rem % 64;
    ekb[i] = (m < 129) ? f2b(ek[((size_t)h * 129 + m) * 64 + d]) : (u16)0;
  }
  if (i < 16 * 64 * 160) {
    int h = i / (64 * 160); int rem = i % (64 * 160); int d = rem / 160; int mm = rem % 160;
    evt[i] = (mm < 129) ? f2b(ev[((size_t)h * 129 + mm) * 64 + d]) : (u16)0;
  }
}

// ---------------- bf16 MFMA GEMM body: C[4096][1024] = A[4096][1024] * Bt[1024][1024]^T --------
// mode 0: bf16 -> [B][H][L][D] (Q/K); mode 1: bf16 -> [B][H][D][L] (V^T); mode 2: f32 + bias
static __device__ __forceinline__ void gemm_body(const u16* __restrict__ A, const u16* __restrict__ Bt,
                                                 void* __restrict__ Cout, const float* __restrict__ bias,
                                                 int mode, int bx, int by) {
  __shared__ u16 As[128 * 32];
  __shared__ u16 Bs[128 * 32];
  int tid = threadIdx.x;
  int w = tid >> 6, lane = tid & 63;
  int wrw = w >> 1, wcw = w & 1, lr = lane & 15, lk = lane >> 4;
  int m0 = by * 128, n0 = bx * 128;
  f32x4 acc[4][4] = {};
  int crow = lane >> 2;          // row within 16-row chunk
  int ccol = (lane & 3) * 8;     // u16 col within 32
  const u16* gA = &A [(size_t)(m0 + w * 32 + crow) * 1024 + ccol];
  const u16* gB = &Bt[(size_t)(n0 + w * 32 + crow) * 1024 + ccol];
  u16* lA = &As[w * 32 * 32];
  u16* lB = &Bs[w * 32 * 32];
  for (int k0 = 0; k0 < 1024; k0 += 32) {
    __syncthreads();
    gload_lds16(gA + k0,             lA);
    gload_lds16(gA + k0 + 16 * 1024, lA + 16 * 32);
    gload_lds16(gB + k0,             lB);
    gload_lds16(gB + k0 + 16 * 1024, lB + 16 * 32);
    __syncthreads();
    s16x8 af[4], bfr[4];
#pragma unroll
    for (int mt = 0; mt < 4; mt++) af[mt]  = *(const s16x8*)&As[(wrw * 64 + mt * 16 + lr) * 32 + lk * 8];
#pragma unroll
    for (int nt = 0; nt < 4; nt++) bfr[nt] = *(const s16x8*)&Bs[(wcw * 64 + nt * 16 + lr) * 32 + lk * 8];
    __builtin_amdgcn_s_setprio(1);
#pragma unroll
    for (int mt = 0; mt < 4; mt++)
#pragma unroll
      for (int nt = 0; nt < 4; nt++)
        acc[mt][nt] = MFMA16(af[mt], bfr[nt], acc[mt][nt]);
    __builtin_amdgcn_s_setprio(0);
  }
#pragma unroll
  for (int mt = 0; mt < 4; mt++)
#pragma unroll
    for (int nt = 0; nt < 4; nt++)
#pragma unroll
      for (int r = 0; r < 4; r++) {
        int row = m0 + wrw * 64 + mt * 16 + lk * 4 + r;
        int col = n0 + wcw * 64 + nt * 16 + lr;
        float v = acc[mt][nt][r];
        if (mode == 2) {
          ((float*)Cout)[(size_t)row * 1024 + col] = v + bias[col];
        } else {
          int bb = row >> 10, l = row & 1023;
          int hh = col >> 6, dd = col & 63;
          if (mode == 0)
            ((u16*)Cout)[((size_t)(bb * 16 + hh)) * 65536 + (size_t)l * 64 + dd] = f2b(v);
          else
            ((u16*)Cout)[((size_t)(bb * 16 + hh)) * 65536 + (size_t)dd * 1024 + l] = f2b(v);
        }
      }
}

__global__ __launch_bounds__(256) void k_gemm_qkv(const u16* __restrict__ A,
                                                  const u16* __restrict__ BtQ, const u16* __restrict__ BtK,
                                                  const u16* __restrict__ BtV,
                                                  u16* __restrict__ Qo, u16* __restrict__ Ko,
                                                  u16* __restrict__ Vo) {
  int z = blockIdx.z;
  const u16* Bt = (z == 0) ? BtQ : (z == 1) ? BtK : BtV;
  u16* Cout     = (z == 0) ? Qo  : (z == 1) ? Ko  : Vo;
  gemm_body(A, Bt, Cout, nullptr, (z == 2) ? 1 : 0, blockIdx.x, blockIdx.y);
}

__global__ __launch_bounds__(256) void k_gemm_out(const u16* __restrict__ A, const u16* __restrict__ Bt,
                                                  float* __restrict__ Cout, const float* __restrict__ bias) {
  gemm_body(A, Bt, Cout, bias, 2, blockIdx.x, blockIdx.y);
}

// ---------------- fused relative-position attention (single-pass, defer-max) ----------------
// Grid: B*H*16 blocks, 256 threads. LDS 73472 B -> 2 blocks/CU.
//   qm_s      @ 0     : 64*133 f32 = 34048
//   P_s       @ 34048 : 64*136 bf16 = 17408
//   wrb       @ 51456 : 64*168 bf16 = 21504   (buckets 0..128 used, rest zero pad)
//   row_scale @ 72960 : 64 f32
//   row_sum   @ 73216 : 64 f32
#define THR_DM 8.0f
__global__ __launch_bounds__(256) void k_attn(const u16* __restrict__ Qg, const u16* __restrict__ Kg,
                                              const u16* __restrict__ Vt, const u16* __restrict__ ekb,
                                              const u16* __restrict__ evt, const float* __restrict__ pmask,
                                              u16* __restrict__ Og) {
  __shared__ alignas(16) char smem[73472];
  float* qm_s      = (float*)smem;
  u16*   P_s       = (u16*)(smem + 34048);
  u16*   wrb       = (u16*)(smem + 51456);
  float* row_scale = (float*)(smem + 72960);
  float* row_sum   = (float*)(smem + 73216);

  int tid = threadIdx.x, w = tid >> 6, lane = tid & 63, lr = lane & 15, lk = lane >> 4;
  int bh = blockIdx.x >> 4, it = blockIdx.x & 15;
  int b = bh >> 4, h = bh & 15;
  int i0 = it * 64;
  int i_base = w * 16 + lk * 4;  // + r gives this thread's 4 output rows

  // zero wrb (64*168 u16 = 5376 uints)
  for (int t = tid; t < 5376; t += 256) ((unsigned*)wrb)[t] = 0u;

  // Q fragments straight to registers
  s16x8 aq[2];
  {
    const u16* qp = &Qg[((size_t)bh * 1024 + i0 + w * 16 + lr) * 64 + lk * 8];
    aq[0] = *(const s16x8*)qp; aq[1] = *(const s16x8*)(qp + 32);
  }

  // qm[i][m] = q_i . ek[h][m]
#pragma unroll
  for (int nt = 0; nt < 9; nt++) {
    f32x4 c = {};
    const u16* ekp = &ekb[((size_t)h * 144 + nt * 16 + lr) * 64 + lk * 8];
    c = MFMA16(aq[0], *(const s16x8*)ekp, c);
    c = MFMA16(aq[1], *(const s16x8*)(ekp + 32), c);
    int mcol = nt * 16 + lr;
    if (mcol < 133) {
#pragma unroll
      for (int r = 0; r < 4; r++) qm_s[(i_base + r) * 133 + mcol] = c[r];
    }
  }
  __syncthreads();

  float mrow[4] = {-3e38f, -3e38f, -3e38f, -3e38f};
  f32x4 oacc[4] = {};
  float lsum = 0.f, rsum = 0.f;
  int iw = tid >> 2, sub = tid & 3, ig = i0 + iw;

  for (int jt = 0; jt < 8; jt++) {
    int j0 = jt * 128;
    float mk[8];
#pragma unroll
    for (int nt = 0; nt < 8; nt++) mk[nt] = pmask[b * 1024 + j0 + nt * 16 + lr] * -1e9f;
    float sv[8][4];
#pragma unroll
    for (int nt = 0; nt < 8; nt++) {
      f32x4 c = {};
      const u16* kp = &Kg[((size_t)bh * 1024 + j0 + nt * 16 + lr) * 64 + lk * 8];
      c = MFMA16(aq[0], *(const s16x8*)kp, c);
      c = MFMA16(aq[1], *(const s16x8*)(kp + 32), c);
      int j = j0 + nt * 16 + lr;
#pragma unroll
      for (int r = 0; r < 4; r++) {
        int dl = j - (i0 + i_base + r);
        dl = dl < -64 ? -64 : (dl > 64 ? 64 : dl);
        sv[nt][r] = (c[r] + qm_s[(i_base + r) * 133 + dl + 64]) * 0.125f + mk[nt];
      }
    }
#pragma unroll
    for (int r = 0; r < 4; r++) {
      float mx = sv[0][r];
#pragma unroll
      for (int nt = 1; nt < 8; nt++) mx = fmaxf(mx, sv[nt][r]);
#pragma unroll
      for (int o = 1; o < 16; o <<= 1) mx = fmaxf(mx, __shfl_xor(mx, o));
      float sc = 1.0f;
      if (mx > mrow[r] + THR_DM) {         // defer-max: rescale only on big growth
        sc = __expf(mrow[r] - mx);
        mrow[r] = mx;
#pragma unroll
        for (int nt = 0; nt < 4; nt++) oacc[nt][r] *= sc;
      }
      if (lr == 0) row_scale[i_base + r] = sc;
#pragma unroll
      for (int nt = 0; nt < 8; nt++)
        P_s[(i_base + r) * 136 + nt * 16 + lr] = f2b(__expf(sv[nt][r] - mrow[r]));
    }
    __syncthreads();

    // PV: oacc[i][d] += P~ . V
    __builtin_amdgcn_s_setprio(1);
    {
      s16x8 ap[4];
#pragma unroll
      for (int kk = 0; kk < 4; kk++) ap[kk] = *(const s16x8*)&P_s[(w * 16 + lr) * 136 + kk * 32 + lk * 8];
#pragma unroll
      for (int nt = 0; nt < 4; nt++) {
        const u16* vp = &Vt[((size_t)bh * 64 + nt * 16 + lr) * 1024 + j0 + lk * 8];
#pragma unroll
        for (int kk = 0; kk < 4; kk++)
          oacc[nt] = MFMA16(ap[kk], *(const s16x8*)(vp + kk * 32), oacc[nt]);
      }
    }
    __builtin_amdgcn_s_setprio(0);

    // wr scatter: interior buckets write-once, edges accumulate in registers
    {
      float sc2 = row_scale[iw];
      if (sc2 != 1.0f) {
        lsum *= sc2; rsum *= sc2;
        unsigned* wrow = (unsigned*)&wrb[iw * 168];
        for (int t = sub; t < 84; t += 4) {
          unsigned vv = wrow[t];
          float lo = b2f((u16)(vv & 0xffffu)) * sc2;
          float hi = b2f((u16)(vv >> 16)) * sc2;
          wrow[t] = (unsigned)f2b(lo) | ((unsigned)f2b(hi) << 16);
        }
      }
      if (j0 + 127 < ig - 63) {            // whole tile left of band
        float s = 0.f;
#pragma unroll
        for (int t = 0; t < 8; t++) {
          ushort4 pv = *(const ushort4*)&P_s[iw * 136 + sub * 32 + t * 4];
          s += b2f(pv.x) + b2f(pv.y) + b2f(pv.z) + b2f(pv.w);
        }
        lsum += s;
      } else if (j0 > ig + 63) {           // whole tile right of band
        float s = 0.f;
#pragma unroll
        for (int t = 0; t < 8; t++) {
          ushort4 pv = *(const ushort4*)&P_s[iw * 136 + sub * 32 + t * 4];
          s += b2f(pv.x) + b2f(pv.y) + b2f(pv.z) + b2f(pv.w);
        }
        rsum += s;
      } else {
        for (int kk = 0; kk < 32; kk++) {
          int jj = kk * 4 + sub;
          float p = b2f(P_s[iw * 136 + jj]);
          int dl = (j0 + jj) - ig;
          if (dl <= -64) lsum += p;
          else if (dl >= 64) rsum += p;
          else wrb[iw * 168 + dl + 64] = f2b(p);
        }
      }
    }
    __syncthreads();
  }

  // edge buckets
  lsum += __shfl_xor(lsum, 1); lsum += __shfl_xor(lsum, 2);
  rsum += __shfl_xor(rsum, 1); rsum += __shfl_xor(rsum, 2);
  if (sub == 0) { wrb[iw * 168] = f2b(lsum); wrb[iw * 168 + 128] = f2b(rsum); }
  __syncthreads();

  // softmax denominator = row-sum of wrb
  {
    float s = 0.f;
#pragma unroll
    for (int t = 0; t < 10; t++) {
      ushort4 pv = *(const ushort4*)&wrb[iw * 168 + t * 16 + sub * 4];
      s += b2f(pv.x) + b2f(pv.y) + b2f(pv.z) + b2f(pv.w);
    }
    s += __shfl_xor(s, 1); s += __shfl_xor(s, 2);
    if (sub == 0) row_sum[iw] = s;
  }
  __syncthreads();

  // oacc += wr . Ev
  __builtin_amdgcn_s_setprio(1);
  {
    s16x8 aw[5];
#pragma unroll
    for (int kk = 0; kk < 5; kk++) aw[kk] = *(const s16x8*)&wrb[(w * 16 + lr) * 168 + kk * 32 + lk * 8];
#pragma unroll
    for (int nt = 0; nt < 4; nt++) {
      const u16* ep = &evt[((size_t)h * 64 + nt * 16 + lr) * 160 + lk * 8];
#pragma unroll
      for (int kk = 0; kk < 5; kk++)
        oacc[nt] = MFMA16(aw[kk], *(const s16x8*)(ep + kk * 32), oacc[nt]);
    }
  }
  __builtin_amdgcn_s_setprio(0);

  // normalize + write O[(b,l)][(h,d)]
#pragma unroll
  for (int nt = 0; nt < 4; nt++)
#pragma unroll
    for (int r = 0; r < 4; r++) {
      int i_loc = i_base + r;
      float v = oacc[nt][r] / row_sum[i_loc];
      Og[((size_t)(b * 1024 + i0 + i_loc)) * 1024 + h * 64 + nt * 16 + lr] = f2b(v);
    }
}

// ---------------- launch ----------------
#define OFF_XB   0u
#define OFF_WQT  8388608u
#define OFF_WKT  10485760u
#define OFF_WVT  12582912u
#define OFF_WOT  14680064u
#define OFF_Q    16777216u
#define OFF_K    25165824u
#define OFF_VT   33554432u
#define OFF_O    41943040u
#define OFF_EKB  50331648u
#define OFF_EVT  50626560u

extern "C" void kernel_launch(void* const* d_in, const int* in_sizes, int n_in,
                              void* d_out, int out_size, void* d_ws, size_t ws_size,
                              hipStream_t stream) {
  const float* x  = (const float*)d_in[0];
  const float* pm = (const float*)d_in[1];
  const float* wq = (const float*)d_in[2];
  const float* wk = (const float*)d_in[3];
  const float* wv = (const float*)d_in[4];
  const float* wo = (const float*)d_in[5];
  const float* bo = (const float*)d_in[6];
  const float* ek = (const float*)d_in[7];
  const float* ev = (const float*)d_in[8];
  char* ws = (char*)d_ws;
  u16* Xb  = (u16*)(ws + OFF_XB);
  u16* Wqt = (u16*)(ws + OFF_WQT);
  u16* Wkt = (u16*)(ws + OFF_WKT);
  u16* Wvt = (u16*)(ws + OFF_WVT);
  u16* Wot = (u16*)(ws + OFF_WOT);
  u16* Qg  = (u16*)(ws + OFF_Q);
  u16* Kg  = (u16*)(ws + OFF_K);
  u16* Vtg = (u16*)(ws + OFF_VT);
  u16* Og  = (u16*)(ws + OFF_O);
  u16* EKB = (u16*)(ws + OFF_EKB);
  u16* EVT = (u16*)(ws + OFF_EVT);

  k_cast_x<<<4096, 256, 0, stream>>>(x, Xb, 1048576);
  {
    dim3 tb(32, 8), tg(32, 32, 4);
    k_transpose_w<<<tg, tb, 0, stream>>>(wq, wk, wv, wo, Wqt, Wkt, Wvt, Wot);
  }
  k_prep_rel<<<640, 256, 0, stream>>>(ek, ev, EKB, EVT);
  {
    dim3 gq(8, 32, 3);
    k_gemm_qkv<<<gq, 256, 0, stream>>>(Xb, Wqt, Wkt, Wvt, Qg, Kg, Vtg);
    k_attn<<<1024, 256, 0, stream>>>(Qg, Kg, Vtg, EKB, EVT, pm, Og);
    dim3 go(8, 32);
    k_gemm_out<<<go, 256, 0, stream>>>(Og, Wot, (float*)d_out, bo);
  }
}